// Round 16
// baseline (231.833 us; speedup 1.0000x reference)
//
#include <hip/hip_runtime.h>
#include <cstdint>

typedef __bf16 bf16;
typedef __bf16 bf16x8 __attribute__((ext_vector_type(8)));
typedef __bf16 bf16x4 __attribute__((ext_vector_type(4)));
typedef float f32x4 __attribute__((ext_vector_type(4)));

#define DEVINL __device__ __forceinline__

namespace {
constexpr int DIM = 1024, HEADS = 8, HD = 128, HALF = 64;
constexpr int SQ = 512;
constexpr int SK = 31290;
constexpr int SKP = 31488;               // 123*256: divisible by 256 for the KV GEMM
constexpr int NSPLIT = 24;               // 768 blocks = 3/CU, all co-resident
constexpr int NCHUNK = 31;               // scan chunks of 1024
constexpr int KVBLKS = 984;              // 123*8 KV-GEMM blocks; +8 Q-proj blocks

// workspace layout (bytes). Opart ALIASES [memb|xb|Wkv] which are dead by attn time.
constexpr long OFF_MEMB = 0;
constexpr long OFF_XB   = OFF_MEMB + (long)SKP * DIM * 2;
constexpr long OFF_WKV  = OFF_XB + (long)SQ * DIM * 2;
constexpr long OFF_WQ   = OFF_WKV + 2048L * DIM * 2;
constexpr long OFF_WO   = OFF_WQ + (long)DIM * DIM * 2;
constexpr long OFF_BKV  = OFF_WO + (long)DIM * DIM * 2;
constexpr long OFF_KPRE = OFF_BKV + 2048L * 4;
constexpr long OFF_VT   = OFF_KPRE + (long)SKP * DIM * 2;
constexpr long OFF_QPRE = OFF_VT + (long)DIM * SKP * 2;
constexpr long OFF_QR   = OFF_QPRE + (long)SQ * DIM * 4;
constexpr long OFF_ML   = OFF_QR + (long)SQ * DIM * 2;
constexpr long OFF_AO   = OFF_ML + (long)NSPLIT * HEADS * SQ * 2 * 4;
constexpr long OFF_IDX  = OFF_AO + (long)SQ * DIM * 2;
constexpr long OFF_NKC  = OFF_IDX + 31744L * 4;
constexpr long OFF_CSM  = OFF_NKC + 64;
constexpr long OFF_OP   = OFF_MEMB;      // bf16: 25MB, < OFF_KPRE: only dead bufs
}

DEVINL void gl_lds16(const void* g, void* l) {
  __builtin_amdgcn_global_load_lds(
      (__attribute__((address_space(1))) void*)(void*)g,
      (__attribute__((address_space(3))) void*)l, 16, 0, 0);
}

// ---------------- mask compaction: parallel 2-kernel stable scan ----------------

__global__ __launch_bounds__(1024) void k_scan1(const int* __restrict__ mask,
                                                int* __restrict__ csum) {
  int tid = threadIdx.x, lane = tid & 63, wv = tid >> 6;
  __shared__ int wsum[16];
  long i = (long)blockIdx.x * 1024 + tid;
  int m = (i < SK) ? (mask[i] != 0) : 0;
  unsigned long long bal = __ballot(m);
  if (lane == 0) wsum[wv] = (int)__popcll(bal);
  __syncthreads();
  if (tid == 0) {
    int tot = 0;
    #pragma unroll
    for (int j = 0; j < 16; ++j) tot += wsum[j];
    csum[blockIdx.x] = tot;
  }
}

__global__ __launch_bounds__(1024) void k_scan3(const int* __restrict__ mask,
                                                const int* __restrict__ csum,
                                                int* __restrict__ idx,
                                                int* __restrict__ nkcp) {
  int tid = threadIdx.x, lane = tid & 63, wv = tid >> 6;
  __shared__ int wsum[16];
  int cb = 0, tot = 0;
  #pragma unroll
  for (int j = 0; j < NCHUNK; ++j) {
    int v = csum[j];
    if (j < (int)blockIdx.x) cb += v;
    tot += v;
  }
  if (blockIdx.x == 0 && tid == 0) *nkcp = tot;
  long i = (long)blockIdx.x * 1024 + tid;
  int m = (i < SK) ? (mask[i] != 0) : 0;
  unsigned long long bal = __ballot(m);
  int wpre = (int)__popcll(bal & ((1ull << lane) - 1ull));
  if (lane == 0) wsum[wv] = (int)__popcll(bal);
  __syncthreads();
  int woff = 0;
  #pragma unroll
  for (int j = 0; j < 16; ++j) woff += (j < wv) ? wsum[j] : 0;
  if (m) idx[cb + woff + wpre] = (int)i;
}

// ---------------- merged convert: gather-cvt mem + all weight/x converts ----------------
// blocks [0, 15744): memb gather-convert; blocks [15744, 18048): prep.

__global__ __launch_bounds__(256) void k_cvtprep(const float* __restrict__ mem,
    const int* __restrict__ idx, const int* __restrict__ nkcp,
    bf16* __restrict__ memb,
    const float* __restrict__ x, const float* __restrict__ Wq,
    const float* __restrict__ Wo, const float* __restrict__ Wk,
    const float* __restrict__ Wv, const float* __restrict__ bk,
    const float* __restrict__ bv, bf16* __restrict__ xb,
    bf16* __restrict__ WqB, bf16* __restrict__ WoB,
    bf16* __restrict__ WkvB, float* __restrict__ bKV) {
  if (blockIdx.x < 15744) {
    long i = (long)blockIdx.x * 256 + threadIdx.x;
    long e = i * 8;
    int row = (int)(e >> 10);
    int nkc = *nkcp;
    int lim = ((((nkc + 63) & ~63) + 255) & ~255);
    if (row >= lim) return;
    bf16x8 o;
    if (row < nkc) {
      long se = ((long)idx[row] << 10) + (e & 1023);
      float4 a = *(const float4*)(mem + se);
      float4 b = *(const float4*)(mem + se + 4);
      o[0] = (bf16)a.x; o[1] = (bf16)a.y; o[2] = (bf16)a.z; o[3] = (bf16)a.w;
      o[4] = (bf16)b.x; o[5] = (bf16)b.y; o[6] = (bf16)b.z; o[7] = (bf16)b.w;
    } else {
      #pragma unroll
      for (int j = 0; j < 8; ++j) o[j] = (bf16)0.0f;
    }
    *(bf16x8*)(memb + e) = o;
    return;
  }
  long i = (long)(blockIdx.x - 15744) * 256 + threadIdx.x;
  constexpr long n_x = 65536, n_w = 131072;        // in 8-elem units
  const float* src;
  bf16* dst;
  long off;
  if (i < n_x) { src = x; dst = xb; off = i; }
  else if (i < n_x + n_w) { src = Wq; dst = WqB; off = i - n_x; }
  else if (i < n_x + 2 * n_w) { src = Wo; dst = WoB; off = i - n_x - n_w; }
  else if (i < n_x + 2 * n_w + 262144) {
    long j = i - n_x - 2 * n_w;
    long e = j * 8;
    int n = (int)(e >> 10);
    const float* s2 = (n < 1024) ? (Wk + e) : (Wv + e - 1024L * 1024);
    float4 a = *(const float4*)(s2);
    float4 b = *(const float4*)(s2 + 4);
    bf16x8 o;
    o[0] = (bf16)a.x; o[1] = (bf16)a.y; o[2] = (bf16)a.z; o[3] = (bf16)a.w;
    o[4] = (bf16)b.x; o[5] = (bf16)b.y; o[6] = (bf16)b.z; o[7] = (bf16)b.w;
    *(bf16x8*)(WkvB + e) = o;
    if (j < 2048) bKV[j] = (j < 1024) ? bk[j] : bv[j - 1024];
    return;
  } else return;
  long e = off * 8;
  float4 a = *(const float4*)(src + e);
  float4 b = *(const float4*)(src + e + 4);
  bf16x8 o;
  o[0] = (bf16)a.x; o[1] = (bf16)a.y; o[2] = (bf16)a.z; o[3] = (bf16)a.w;
  o[4] = (bf16)b.x; o[5] = (bf16)b.y; o[6] = (bf16)b.z; o[7] = (bf16)b.w;
  *(bf16x8*)(dst + e) = o;
}

// ---------------- small GEMM (O proj): 128x128 tile, m97 structure ----------------

__global__ __launch_bounds__(256, 2)
void k_gemm(const bf16* __restrict__ A, const bf16* __restrict__ B,
            const float* __restrict__ bias, int Ntiles,
            float* __restrict__ outF, int ldF) {
  constexpr int K = 1024;
  __shared__ char lds[32768];
  char* ldsA = lds;
  char* ldsB = lds + 16384;
  int tid = threadIdx.x;
  int w = tid >> 6, lane = tid & 63;
  int cpx = gridDim.x >> 3;
  int bid = (blockIdx.x & 7) * cpx + (blockIdx.x >> 3);
  int mt = bid / Ntiles, nt = bid % Ntiles;
  int m0 = mt * 128, n0 = nt * 128;
  int wm = w >> 1, wn = w & 1;
  int cl = lane & 15, rg = lane >> 4;

  f32x4 acc[4][4] = {};

  int rowi = lane >> 3, g = lane & 7;
  for (int kt = 0; kt < K / 64; ++kt) {
    #pragma unroll
    for (int j = 0; j < 4; ++j) {
      int rb = (w * 4 + j) * 8;
      int row = rb + rowi;
      int gs = g ^ (row & 7);
      gl_lds16((const char*)(A + (long)(m0 + row) * K + kt * 64) + gs * 16, ldsA + rb * 128);
      gl_lds16((const char*)(B + (long)(n0 + row) * K + kt * 64) + gs * 16, ldsB + rb * 128);
    }
    __syncthreads();
    #pragma unroll
    for (int ks = 0; ks < 2; ++ks) {
      bf16x8 af[4], bfr[4];
      #pragma unroll
      for (int i = 0; i < 4; ++i) {
        int rowA = wm * 64 + i * 16 + cl;
        int c = ks * 4 + rg;
        af[i] = *(const bf16x8*)(ldsA + rowA * 128 + ((c ^ (rowA & 7)) * 16));
        int rowB = wn * 64 + i * 16 + cl;
        bfr[i] = *(const bf16x8*)(ldsB + rowB * 128 + ((c ^ (rowB & 7)) * 16));
      }
      #pragma unroll
      for (int mf = 0; mf < 4; ++mf)
        #pragma unroll
        for (int nf = 0; nf < 4; ++nf)
          acc[mf][nf] = __builtin_amdgcn_mfma_f32_16x16x32_bf16(af[mf], bfr[nf], acc[mf][nf], 0, 0, 0);
    }
    __syncthreads();
  }

  #pragma unroll
  for (int mf = 0; mf < 4; ++mf) {
    #pragma unroll
    for (int nf = 0; nf < 4; ++nf) {
      int n = n0 + wn * 64 + nf * 16 + cl;
      float bval = bias[n];
      int mb = m0 + wm * 64 + mf * 16 + rg * 4;
      #pragma unroll
      for (int rr = 0; rr < 4; ++rr)
        outF[(long)(mb + rr) * ldF + n] = acc[mf][nf][rr] + bval;
    }
  }
}

// ---------------- KV GEMM + folded Q-proj: 256x256 tile, BK=64, 8 waves ----------------
// Blocks [0,984): KV GEMM (nt == XCD via hw %8). Blocks [984,992): Q-proj
// (A=xb 512 rows, B=WqB, f32 Qpre epilogue) — runs concurrently with KV round 1.

#define KV_PHASE(P)                                                                   \
  {                                                                                   \
    bf16x8 a00 = dsA(cur, 2 * (P), 0),     a01 = dsA(cur, 2 * (P), 1);                \
    bf16x8 a10 = dsA(cur, 2 * (P) + 1, 0), a11 = dsA(cur, 2 * (P) + 1, 1);            \
    __builtin_amdgcn_s_setprio(1);                                                    \
    _Pragma("unroll")                                                                 \
    for (int nf = 0; nf < 4; ++nf) {                                                  \
      acc[2 * (P)][nf]     = __builtin_amdgcn_mfma_f32_16x16x32_bf16(a00, bb[nf][0], acc[2 * (P)][nf], 0, 0, 0);     \
      acc[2 * (P) + 1][nf] = __builtin_amdgcn_mfma_f32_16x16x32_bf16(a10, bb[nf][0], acc[2 * (P) + 1][nf], 0, 0, 0); \
    }                                                                                 \
    _Pragma("unroll")                                                                 \
    for (int nf = 0; nf < 4; ++nf) {                                                  \
      acc[2 * (P)][nf]     = __builtin_amdgcn_mfma_f32_16x16x32_bf16(a01, bb[nf][1], acc[2 * (P)][nf], 0, 0, 0);     \
      acc[2 * (P) + 1][nf] = __builtin_amdgcn_mfma_f32_16x16x32_bf16(a11, bb[nf][1], acc[2 * (P) + 1][nf], 0, 0, 0); \
    }                                                                                 \
    __builtin_amdgcn_s_setprio(0);                                                    \
  }

__global__ __launch_bounds__(512)
void k_gemm_kv(const bf16* __restrict__ A, const bf16* __restrict__ B,
               const float* __restrict__ bias, const int* __restrict__ nkcp,
               bf16* __restrict__ outK, bf16* __restrict__ outVT,
               const bf16* __restrict__ Aq, const bf16* __restrict__ Bq,
               const float* __restrict__ bq, float* __restrict__ Qpre) {
  constexpr int K = 1024, NTK = 16;
  __shared__ char lds[131072];
  const int tid = threadIdx.x;
  const int w = tid >> 6, lane = tid & 63;
  const bool isQ = blockIdx.x >= KVBLKS;
  int mt, nt;
  const bf16 *Asrc, *Bsrc;
  if (isQ) {
    int qb2 = blockIdx.x - KVBLKS;
    mt = qb2 >> 2; nt = qb2 & 3;
    Asrc = Aq; Bsrc = Bq;
  } else {
    mt = blockIdx.x >> 3; nt = blockIdx.x & 7;   // nt == XCD (hw %8)
    if (mt * 256 >= ((*nkcp + 63) & ~63)) return;
    Asrc = A; Bsrc = B;
  }
  const int m0 = mt * 256, n0 = nt * 256;
  const int wm = w >> 2, wn = w & 3;
  const int cl = lane & 15, rg = lane >> 4;
  const int srow = lane >> 3, sg = lane & 7;

  f32x4 acc[8][4] = {};

  auto stage = [&](int b, int kt, int isB, int cr) {
    const bf16* src = isB ? Bsrc : Asrc;
    int r = cr + w * 8 + srow;
    int gs = sg ^ (r & 7);
    const char* gp = (const char*)(src + (long)((isB ? n0 : m0) + r) * K + kt * 64) + gs * 16;
    char* lp = lds + b * 65536 + isB * 32768 + (cr + w * 8) * 128;
    gl_lds16(gp, lp);
  };
  auto dsA = [&](int b, int mf, int ks) -> bf16x8 {
    int r = wm * 128 + mf * 16 + cl;
    int c = ks * 4 + rg;
    return *(const bf16x8*)(lds + b * 65536 + r * 128 + ((c ^ (r & 7)) * 16));
  };
  auto dsB = [&](int b, int nf, int ks) -> bf16x8 {
    int r = wn * 64 + nf * 16 + cl;
    int c = ks * 4 + rg;
    return *(const bf16x8*)(lds + b * 65536 + 32768 + r * 128 + ((c ^ (r & 7)) * 16));
  };

  stage(0, 0, 1, 0);   stage(0, 0, 1, 64);
  stage(0, 0, 1, 128); stage(0, 0, 1, 192);
  stage(0, 0, 0, 0);   stage(0, 0, 0, 128);
  stage(0, 0, 0, 64);  stage(0, 0, 0, 192);

  for (int t = 0; t < NTK; ++t) {
    const int cur = t & 1, nxt = cur ^ 1;
    const bool pre = (t + 1 < NTK);
    bf16x8 bb[4][2];

    if (pre) {
      stage(nxt, t + 1, 1, 0); stage(nxt, t + 1, 1, 64);
      asm volatile("s_waitcnt vmcnt(4)\ns_barrier" ::: "memory");
    } else {
      asm volatile("s_waitcnt vmcnt(2)\ns_barrier" ::: "memory");
    }
    #pragma unroll
    for (int nf = 0; nf < 4; ++nf) { bb[nf][0] = dsB(cur, nf, 0); bb[nf][1] = dsB(cur, nf, 1); }
    KV_PHASE(0)
    if (pre) {
      stage(nxt, t + 1, 1, 128); stage(nxt, t + 1, 1, 192);
      stage(nxt, t + 1, 0, 0);   stage(nxt, t + 1, 0, 128);
    }
    KV_PHASE(1)
    if (pre) {
      stage(nxt, t + 1, 0, 64); stage(nxt, t + 1, 0, 192);
      asm volatile("s_waitcnt vmcnt(8)\ns_barrier" ::: "memory");
    } else {
      asm volatile("s_waitcnt vmcnt(0)\ns_barrier" ::: "memory");
    }
    KV_PHASE(2)
    KV_PHASE(3)
    asm volatile("s_barrier" ::: "memory");   // dbuf WAR guard
  }

  if (isQ) {
    #pragma unroll
    for (int mf = 0; mf < 8; ++mf)
      #pragma unroll
      for (int nf = 0; nf < 4; ++nf) {
        int n = n0 + wn * 64 + nf * 16 + cl;
        float bval = bq[n];
        int mrow = m0 + wm * 128 + mf * 16 + rg * 4;
        #pragma unroll
        for (int rr = 0; rr < 4; ++rr)
          Qpre[(long)(mrow + rr) * 1024 + n] = acc[mf][nf][rr] + bval;
      }
  } else if (nt < 4) {
    #pragma unroll
    for (int mf = 0; mf < 8; ++mf)
      #pragma unroll
      for (int nf = 0; nf < 4; ++nf) {
        int n = n0 + wn * 64 + nf * 16 + cl;
        float bval = bias[n];
        int mrow = m0 + wm * 128 + mf * 16 + rg * 4;
        #pragma unroll
        for (int rr = 0; rr < 4; ++rr)
          outK[(long)(mrow + rr) * 1024 + n] = (bf16)(acc[mf][nf][rr] + bval);
      }
  } else {
    #pragma unroll
    for (int mf = 0; mf < 8; ++mf)
      #pragma unroll
      for (int nf = 0; nf < 4; ++nf) {
        int n = n0 + wn * 64 + nf * 16 + cl;
        float bval = bias[n];
        int mrow = m0 + wm * 128 + mf * 16 + rg * 4;
        bf16x4 pk;
        #pragma unroll
        for (int rr = 0; rr < 4; ++rr) pk[rr] = (bf16)(acc[mf][nf][rr] + bval);
        *(bf16x4*)(outVT + (long)(n - 1024) * SKP + mrow) = pk;
      }
  }
}

// ---------------- merged rmsnorm + rope (Q rows then K rows) ----------------

__global__ __launch_bounds__(256) void k_fuse_qk(const float* __restrict__ QP,
    bf16* __restrict__ Qr, const float* __restrict__ gq,
    const float* __restrict__ cosQ, const float* __restrict__ sinQ,
    bf16* __restrict__ KP, const float* __restrict__ gk,
    const float* __restrict__ cosK, const float* __restrict__ sinK,
    const int* __restrict__ idx, const int* __restrict__ nkcp) {
  int bid = blockIdx.x, tid = threadIdx.x;
  int d0 = tid * 4;
  __shared__ float red[4];
  float v0, v1, v2, v3;
  const float *gg, *cosT, *sinT;
  long trow;
  bool isQ = bid < SQ;
  int row;
  if (isQ) {
    row = bid;
    float4 t = *(const float4*)(QP + (long)row * DIM + d0);
    v0 = t.x; v1 = t.y; v2 = t.z; v3 = t.w;
    gg = gq; cosT = cosQ; sinT = sinQ; trow = row;
  } else {
    row = bid - SQ;
    int nkc = *nkcp;
    if (row >= ((nkc + 63) & ~63)) return;
    bf16x4 t = *(const bf16x4*)(KP + (long)row * DIM + d0);
    v0 = (float)t[0]; v1 = (float)t[1]; v2 = (float)t[2]; v3 = (float)t[3];
    gg = gk; cosT = cosK; sinT = sinK;
    trow = (row < nkc) ? idx[row] : 0;
  }
  float ss = v0 * v0 + v1 * v1 + v2 * v2 + v3 * v3;
  #pragma unroll
  for (int m = 1; m < 64; m <<= 1) ss += __shfl_xor(ss, m);
  if ((tid & 63) == 0) red[tid >> 6] = ss;
  __syncthreads();
  float rn = rsqrtf((red[0] + red[1] + red[2] + red[3]) * (1.0f / DIM) + 1e-6f);
  v0 *= rn * gg[d0]; v1 *= rn * gg[d0 + 1]; v2 *= rn * gg[d0 + 2]; v3 *= rn * gg[d0 + 3];
  int i0 = (d0 & 127) >> 1;
  float c0 = cosT[trow * HALF + i0], s0 = sinT[trow * HALF + i0];
  float c1 = cosT[trow * HALF + i0 + 1], s1 = sinT[trow * HALF + i0 + 1];
  bf16x4 o = { (bf16)(v0 * c0 - v1 * s0), (bf16)(v0 * s0 + v1 * c0),
               (bf16)(v2 * c1 - v3 * s1), (bf16)(v2 * s1 + v3 * c1) };
  if (isQ) *(bf16x4*)(Qr + (long)row * DIM + d0) = o;
  else     *(bf16x4*)(KP + (long)row * DIM + d0) = o;
}

// ---------------- flash attention: swapped QK^T + split-wait staging ----------------

__global__ __launch_bounds__(256, 2)
void k_attn(const bf16* __restrict__ Kr, const bf16* __restrict__ VT,
            const bf16* __restrict__ Qr, const int* __restrict__ nkcp,
            bf16* __restrict__ Opart, float* __restrict__ ml) {
  __shared__ char lds[51200];
  char* ldsK = lds;            // [64 keys][256 B]
  char* ldsV = lds + 16384;    // [128 d][128 B]
  int tid = threadIdx.x, w = tid >> 6, lane = tid & 63;
  char* ldsP = lds + 32768 + w * 4608;  // per-wave [32 q][144 B]
  int bid = blockIdx.x;
  int swz = (bid & 7) * 96 + (bid >> 3);  // XCD-chunked
  int sp = swz >> 5, h = (swz >> 2) & 7, qb = swz & 3;
  int nkc = *nkcp;
  int NTC = (nkc + 63) >> 6;
  int t0 = (sp * NTC) / NSPLIT;
  int t1 = ((sp + 1) * NTC) / NSPLIT;
  int cl = lane & 15, rg = lane >> 4;
  int qbase = qb * 128 + w * 32;

  bf16x8 qf[2][4];
  #pragma unroll
  for (int mf = 0; mf < 2; ++mf)
    #pragma unroll
    for (int ks = 0; ks < 4; ++ks)
      qf[mf][ks] = *(const bf16x8*)(Qr + (long)(qbase + mf * 16 + cl) * DIM + h * HD + ks * 32 + rg * 8);

  f32x4 Oa[2][8] = {};
  float m_r[2] = {-1e30f, -1e30f};
  float l_r[2] = {0.f, 0.f};

  const float sc = 0.08838834764831845f;
  for (int t = t0; t < t1; ++t) {
    int k0 = t * 64;
    __syncthreads();   // WAR: all waves done reading previous tile's K/V
    {
      int rK = lane >> 4, gK = lane & 15;
      #pragma unroll
      for (int j = 0; j < 4; ++j) {
        int rb = w * 16 + j * 4;
        int row = rb + rK;
        int gs = gK ^ (row & 7);
        gl_lds16((const char*)(Kr + (long)(k0 + row) * DIM + h * HD) + gs * 16,
                 ldsK + rb * 256);
      }
      int rV = lane >> 3, gV = lane & 7;
      #pragma unroll
      for (int j = 0; j < 4; ++j) {
        int db = w * 32 + j * 8;
        int d = db + rV;
        int gs = gV ^ (d & 7);
        gl_lds16((const char*)(VT + (long)(h * HD + d) * SKP + k0) + gs * 16,
                 ldsV + db * 128);
      }
    }
    asm volatile("s_waitcnt vmcnt(4)\ns_barrier" ::: "memory");  // K ready; V in flight

    f32x4 sa[2][4] = {};
    #pragma unroll
    for (int ks = 0; ks < 4; ++ks) {
      #pragma unroll
      for (int nf = 0; nf < 4; ++nf) {
        int key = nf * 16 + cl;
        int c = ks * 4 + rg;
        bf16x8 kb = *(const bf16x8*)(ldsK + key * 256 + ((c ^ (key & 7)) * 16));
        sa[0][nf] = __builtin_amdgcn_mfma_f32_16x16x32_bf16(kb, qf[0][ks], sa[0][nf], 0, 0, 0);
        sa[1][nf] = __builtin_amdgcn_mfma_f32_16x16x32_bf16(kb, qf[1][ks], sa[1][nf], 0, 0, 0);
      }
    }

    #pragma unroll
    for (int mf = 0; mf < 2; ++mf) {
      #pragma unroll
      for (int nf = 0; nf < 4; ++nf)
        #pragma unroll
        for (int r = 0; r < 4; ++r) {
          int key = k0 + nf * 16 + rg * 4 + r;
          sa[mf][nf][r] = (key < nkc) ? sa[mf][nf][r] * sc : -1e30f;
        }
      float mx = sa[mf][0][0];
      #pragma unroll
      for (int nf = 0; nf < 4; ++nf)
        #pragma unroll
        for (int r = 0; r < 4; ++r) mx = fmaxf(mx, sa[mf][nf][r]);
      mx = fmaxf(mx, __shfl_xor(mx, 16));
      mx = fmaxf(mx, __shfl_xor(mx, 32));
      bool grew = mx > m_r[mf] + 6.0f;
      if (__any(grew)) {
        float mn = grew ? mx : m_r[mf];
        float scl = __expf(m_r[mf] - mn);
        m_r[mf] = mn;
        l_r[mf] *= scl;
        int sb = lane & 48;
        float s0 = __shfl(scl, sb | (rg * 4 + 0));
        float s1 = __shfl(scl, sb | (rg * 4 + 1));
        float s2 = __shfl(scl, sb | (rg * 4 + 2));
        float s3 = __shfl(scl, sb | (rg * 4 + 3));
        #pragma unroll
        for (int df = 0; df < 8; ++df) {
          Oa[mf][df][0] *= s0; Oa[mf][df][1] *= s1;
          Oa[mf][df][2] *= s2; Oa[mf][df][3] *= s3;
        }
      }
      float rsum = 0.f;
      #pragma unroll
      for (int nf = 0; nf < 4; ++nf)
        #pragma unroll
        for (int r = 0; r < 4; ++r) {
          float p = __expf(sa[mf][nf][r] - m_r[mf]);
          sa[mf][nf][r] = p;
          rsum += p;
        }
      rsum += __shfl_xor(rsum, 16);
      rsum += __shfl_xor(rsum, 32);
      l_r[mf] += rsum;
      char* prow = ldsP + (mf * 16 + cl) * 144;
      #pragma unroll
      for (int nf = 0; nf < 4; ++nf) {
        bf16x4 pk = { (bf16)sa[mf][nf][0], (bf16)sa[mf][nf][1],
                      (bf16)sa[mf][nf][2], (bf16)sa[mf][nf][3] };
        *(bf16x4*)(prow + nf * 32 + rg * 8) = pk;
      }
    }

    asm volatile("s_waitcnt vmcnt(0)\ns_barrier" ::: "memory");  // V ready

    #pragma unroll
    for (int ks = 0; ks < 2; ++ks) {
      bf16x8 pa0 = *(const bf16x8*)(ldsP + cl * 144 + ks * 64 + rg * 16);
      bf16x8 pa1 = *(const bf16x8*)(ldsP + (16 + cl) * 144 + ks * 64 + rg * 16);
      int c = ks * 4 + rg;
      #pragma unroll
      for (int df = 0; df < 8; ++df) {
        int d = df * 16 + cl;
        bf16x8 vb = *(const bf16x8*)(ldsV + d * 128 + ((c ^ (d & 7)) * 16));
        Oa[0][df] = __builtin_amdgcn_mfma_f32_16x16x32_bf16(pa0, vb, Oa[0][df], 0, 0, 0);
        Oa[1][df] = __builtin_amdgcn_mfma_f32_16x16x32_bf16(pa1, vb, Oa[1][df], 0, 0, 0);
      }
    }
  }

  long rowb = (long)(sp * HEADS + h) * SQ + qbase;
  #pragma unroll
  for (int mf = 0; mf < 2; ++mf) {
    #pragma unroll
    for (int df = 0; df < 8; ++df)
      #pragma unroll
      for (int r = 0; r < 4; ++r) {
        int qr = mf * 16 + rg * 4 + r;
        Opart[(rowb + qr) * HD + df * 16 + cl] = (bf16)Oa[mf][df][r];
      }
  }
  if (rg == 0) {
    #pragma unroll
    for (int mf = 0; mf < 2; ++mf) {
      ml[(rowb + mf * 16 + cl) * 2] = m_r[mf];
      ml[(rowb + mf * 16 + cl) * 2 + 1] = l_r[mf];
    }
  }
}

__global__ __launch_bounds__(128) void k_combine(const bf16* __restrict__ Opart,
    const float* __restrict__ ml, bf16* __restrict__ AO) {
  int bid = blockIdx.x;
  int h = bid >> 9, qq = bid & 511;
  int d = threadIdx.x;
  float M = -1e30f;
  #pragma unroll 4
  for (int s2 = 0; s2 < NSPLIT; ++s2) {
    long mi = (long)(s2 * HEADS + h) * SQ + qq;
    M = fmaxf(M, ml[mi * 2]);
  }
  float L = 0.f, acc = 0.f;
  #pragma unroll 4
  for (int s2 = 0; s2 < NSPLIT; ++s2) {
    long mi = (long)(s2 * HEADS + h) * SQ + qq;
    float wgt = __expf(ml[mi * 2] - M);
    L += wgt * ml[mi * 2 + 1];
    acc += wgt * (float)Opart[mi * HD + d];
  }
  AO[(long)qq * DIM + h * HD + d] = (bf16)(acc / L);
}

// ---------------- host ----------------

extern "C" void kernel_launch(void* const* d_in, const int* in_sizes, int n_in,
                              void* d_out, int out_size, void* d_ws, size_t ws_size,
                              hipStream_t stream) {
  const float* x     = (const float*)d_in[0];
  const float* mem   = (const float*)d_in[1];
  const int*   mask  = (const int*)d_in[2];
  const float* cos_q = (const float*)d_in[3];
  const float* sin_q = (const float*)d_in[4];
  const float* cos_k = (const float*)d_in[5];
  const float* sin_k = (const float*)d_in[6];
  const float* Wq    = (const float*)d_in[7];
  const float* bq    = (const float*)d_in[8];
  const float* Wk    = (const float*)d_in[9];
  const float* bk    = (const float*)d_in[10];
  const float* Wv    = (const float*)d_in[11];
  const float* bv    = (const float*)d_in[12];
  const float* Wo    = (const float*)d_in[13];
  const float* bo    = (const float*)d_in[14];
  const float* gq    = (const float*)d_in[15];
  const float* gk    = (const float*)d_in[16];

  char* ws = (char*)d_ws;
  bf16*  memb = (bf16*)(ws + OFF_MEMB);
  bf16*  xb   = (bf16*)(ws + OFF_XB);
  bf16*  WkvB = (bf16*)(ws + OFF_WKV);
  bf16*  WqB  = (bf16*)(ws + OFF_WQ);
  bf16*  WoB  = (bf16*)(ws + OFF_WO);
  float* bKV  = (float*)(ws + OFF_BKV);
  bf16*  Kpre = (bf16*)(ws + OFF_KPRE);
  bf16*  VT   = (bf16*)(ws + OFF_VT);
  float* Qpre = (float*)(ws + OFF_QPRE);
  bf16*  Qr   = (bf16*)(ws + OFF_QR);
  bf16*  Opart= (bf16*)(ws + OFF_OP);
  float* mlb  = (float*)(ws + OFF_ML);
  bf16*  AO   = (bf16*)(ws + OFF_AO);
  int*   idx  = (int*)(ws + OFF_IDX);
  int*   nkcp = (int*)(ws + OFF_NKC);
  int*   csum = (int*)(ws + OFF_CSM);

  k_scan1<<<dim3(NCHUNK), dim3(1024), 0, stream>>>(mask, csum);
  k_scan3<<<dim3(NCHUNK), dim3(1024), 0, stream>>>(mask, csum, idx, nkcp);
  k_cvtprep<<<dim3(18048), dim3(256), 0, stream>>>(mem, idx, nkcp, memb,
      x, Wq, Wo, Wk, Wv, bk, bv, xb, WqB, WoB, WkvB, bKV);

  k_gemm_kv<<<dim3(KVBLKS + 8), dim3(512), 0, stream>>>(memb, WkvB, bKV, nkcp,
      Kpre, VT, xb, WqB, bq, Qpre);

  k_fuse_qk<<<dim3(SQ + SKP), dim3(256), 0, stream>>>(Qpre, Qr, gq, cos_q, sin_q,
      Kpre, gk, cos_k, sin_k, idx, nkcp);

  k_attn<<<dim3(NSPLIT * HEADS * 4), dim3(256), 0, stream>>>(Kpre, VT, Qr, nkcp, Opart, mlb);
  k_combine<<<dim3(HEADS * SQ), dim3(128), 0, stream>>>(Opart, mlb, AO);

  k_gemm<<<dim3(4 * 8), dim3(256), 0, stream>>>(AO, WoB, bo, 8, (float*)d_out, DIM);
  (void)in_sizes; (void)n_in; (void)out_size; (void)ws_size;
}

// Round 17
// 224.707 us; speedup vs baseline: 1.0317x; 1.0317x over previous
//
#include <hip/hip_runtime.h>
#include <cstdint>

typedef __bf16 bf16;
typedef __bf16 bf16x8 __attribute__((ext_vector_type(8)));
typedef __bf16 bf16x4 __attribute__((ext_vector_type(4)));
typedef float f32x4 __attribute__((ext_vector_type(4)));

#define DEVINL __device__ __forceinline__

namespace {
constexpr int DIM = 1024, HEADS = 8, HD = 128, HALF = 64;
constexpr int SQ = 512;
constexpr int SK = 31290;
constexpr int SKP = 31488;               // 123*256: divisible by 256 for the KV GEMM
constexpr int NSPLIT = 24;               // 768 blocks = 3/CU, all co-resident
constexpr int NCHUNK = 31;               // scan chunks of 1024

// workspace layout (bytes). Opart ALIASES [memb|xb|Wkv] which are dead by attn time.
constexpr long OFF_MEMB = 0;
constexpr long OFF_XB   = OFF_MEMB + (long)SKP * DIM * 2;
constexpr long OFF_WKV  = OFF_XB + (long)SQ * DIM * 2;
constexpr long OFF_WQ   = OFF_WKV + 2048L * DIM * 2;
constexpr long OFF_WO   = OFF_WQ + (long)DIM * DIM * 2;
constexpr long OFF_BKV  = OFF_WO + (long)DIM * DIM * 2;
constexpr long OFF_KPRE = OFF_BKV + 2048L * 4;
constexpr long OFF_VT   = OFF_KPRE + (long)SKP * DIM * 2;
constexpr long OFF_QPRE = OFF_VT + (long)DIM * SKP * 2;
constexpr long OFF_QR   = OFF_QPRE + (long)SQ * DIM * 4;
constexpr long OFF_ML   = OFF_QR + (long)SQ * DIM * 2;
constexpr long OFF_AO   = OFF_ML + (long)NSPLIT * HEADS * SQ * 2 * 4;
constexpr long OFF_IDX  = OFF_AO + (long)SQ * DIM * 2;
constexpr long OFF_NKC  = OFF_IDX + 31744L * 4;
constexpr long OFF_CSM  = OFF_NKC + 64;
constexpr long OFF_OP   = OFF_MEMB;      // bf16: 25MB, < OFF_KPRE: only dead bufs
}

DEVINL void gl_lds16(const void* g, void* l) {
  __builtin_amdgcn_global_load_lds(
      (__attribute__((address_space(1))) void*)(void*)g,
      (__attribute__((address_space(3))) void*)l, 16, 0, 0);
}

// ---------------- mask compaction: parallel 2-kernel stable scan ----------------

__global__ __launch_bounds__(1024) void k_scan1(const int* __restrict__ mask,
                                                int* __restrict__ csum) {
  int tid = threadIdx.x, lane = tid & 63, wv = tid >> 6;
  __shared__ int wsum[16];
  long i = (long)blockIdx.x * 1024 + tid;
  int m = (i < SK) ? (mask[i] != 0) : 0;
  unsigned long long bal = __ballot(m);
  if (lane == 0) wsum[wv] = (int)__popcll(bal);
  __syncthreads();
  if (tid == 0) {
    int tot = 0;
    #pragma unroll
    for (int j = 0; j < 16; ++j) tot += wsum[j];
    csum[blockIdx.x] = tot;
  }
}

__global__ __launch_bounds__(1024) void k_scan3(const int* __restrict__ mask,
                                                const int* __restrict__ csum,
                                                int* __restrict__ idx,
                                                int* __restrict__ nkcp) {
  int tid = threadIdx.x, lane = tid & 63, wv = tid >> 6;
  __shared__ int wsum[16];
  int cb = 0, tot = 0;
  #pragma unroll
  for (int j = 0; j < NCHUNK; ++j) {
    int v = csum[j];
    if (j < (int)blockIdx.x) cb += v;
    tot += v;
  }
  if (blockIdx.x == 0 && tid == 0) *nkcp = tot;
  long i = (long)blockIdx.x * 1024 + tid;
  int m = (i < SK) ? (mask[i] != 0) : 0;
  unsigned long long bal = __ballot(m);
  int wpre = (int)__popcll(bal & ((1ull << lane) - 1ull));
  if (lane == 0) wsum[wv] = (int)__popcll(bal);
  __syncthreads();
  int woff = 0;
  #pragma unroll
  for (int j = 0; j < 16; ++j) woff += (j < wv) ? wsum[j] : 0;
  if (m) idx[cb + woff + wpre] = (int)i;
}

// ---------------- merged convert: gather-cvt mem + all weight/x converts ----------------
// blocks [0, 15744): memb gather-convert; blocks [15744, 18048): prep.

__global__ __launch_bounds__(256) void k_cvtprep(const float* __restrict__ mem,
    const int* __restrict__ idx, const int* __restrict__ nkcp,
    bf16* __restrict__ memb,
    const float* __restrict__ x, const float* __restrict__ Wq,
    const float* __restrict__ Wo, const float* __restrict__ Wk,
    const float* __restrict__ Wv, const float* __restrict__ bk,
    const float* __restrict__ bv, bf16* __restrict__ xb,
    bf16* __restrict__ WqB, bf16* __restrict__ WoB,
    bf16* __restrict__ WkvB, float* __restrict__ bKV) {
  if (blockIdx.x < 15744) {
    long i = (long)blockIdx.x * 256 + threadIdx.x;
    long e = i * 8;
    int row = (int)(e >> 10);
    int nkc = *nkcp;
    int lim = ((((nkc + 63) & ~63) + 255) & ~255);
    if (row >= lim) return;
    bf16x8 o;
    if (row < nkc) {
      long se = ((long)idx[row] << 10) + (e & 1023);
      float4 a = *(const float4*)(mem + se);
      float4 b = *(const float4*)(mem + se + 4);
      o[0] = (bf16)a.x; o[1] = (bf16)a.y; o[2] = (bf16)a.z; o[3] = (bf16)a.w;
      o[4] = (bf16)b.x; o[5] = (bf16)b.y; o[6] = (bf16)b.z; o[7] = (bf16)b.w;
    } else {
      #pragma unroll
      for (int j = 0; j < 8; ++j) o[j] = (bf16)0.0f;
    }
    *(bf16x8*)(memb + e) = o;
    return;
  }
  long i = (long)(blockIdx.x - 15744) * 256 + threadIdx.x;
  constexpr long n_x = 65536, n_w = 131072;        // in 8-elem units
  const float* src;
  bf16* dst;
  long off;
  if (i < n_x) { src = x; dst = xb; off = i; }
  else if (i < n_x + n_w) { src = Wq; dst = WqB; off = i - n_x; }
  else if (i < n_x + 2 * n_w) { src = Wo; dst = WoB; off = i - n_x - n_w; }
  else if (i < n_x + 2 * n_w + 262144) {
    long j = i - n_x - 2 * n_w;
    long e = j * 8;
    int n = (int)(e >> 10);
    const float* s2 = (n < 1024) ? (Wk + e) : (Wv + e - 1024L * 1024);
    float4 a = *(const float4*)(s2);
    float4 b = *(const float4*)(s2 + 4);
    bf16x8 o;
    o[0] = (bf16)a.x; o[1] = (bf16)a.y; o[2] = (bf16)a.z; o[3] = (bf16)a.w;
    o[4] = (bf16)b.x; o[5] = (bf16)b.y; o[6] = (bf16)b.z; o[7] = (bf16)b.w;
    *(bf16x8*)(WkvB + e) = o;
    if (j < 2048) bKV[j] = (j < 1024) ? bk[j] : bv[j - 1024];
    return;
  } else return;
  long e = off * 8;
  float4 a = *(const float4*)(src + e);
  float4 b = *(const float4*)(src + e + 4);
  bf16x8 o;
  o[0] = (bf16)a.x; o[1] = (bf16)a.y; o[2] = (bf16)a.z; o[3] = (bf16)a.w;
  o[4] = (bf16)b.x; o[5] = (bf16)b.y; o[6] = (bf16)b.z; o[7] = (bf16)b.w;
  *(bf16x8*)(dst + e) = o;
}

// ---------------- small GEMM (Q-proj / O-proj): 128x128 tile, m97 structure ----------------

__global__ __launch_bounds__(256, 2)
void k_gemm(const bf16* __restrict__ A, const bf16* __restrict__ B,
            const float* __restrict__ bias, int Ntiles,
            float* __restrict__ outF, int ldF) {
  constexpr int K = 1024;
  __shared__ char lds[32768];
  char* ldsA = lds;
  char* ldsB = lds + 16384;
  int tid = threadIdx.x;
  int w = tid >> 6, lane = tid & 63;
  int cpx = gridDim.x >> 3;
  int bid = (blockIdx.x & 7) * cpx + (blockIdx.x >> 3);
  int mt = bid / Ntiles, nt = bid % Ntiles;
  int m0 = mt * 128, n0 = nt * 128;
  int wm = w >> 1, wn = w & 1;
  int cl = lane & 15, rg = lane >> 4;

  f32x4 acc[4][4] = {};

  int rowi = lane >> 3, g = lane & 7;
  for (int kt = 0; kt < K / 64; ++kt) {
    #pragma unroll
    for (int j = 0; j < 4; ++j) {
      int rb = (w * 4 + j) * 8;
      int row = rb + rowi;
      int gs = g ^ (row & 7);
      gl_lds16((const char*)(A + (long)(m0 + row) * K + kt * 64) + gs * 16, ldsA + rb * 128);
      gl_lds16((const char*)(B + (long)(n0 + row) * K + kt * 64) + gs * 16, ldsB + rb * 128);
    }
    __syncthreads();
    #pragma unroll
    for (int ks = 0; ks < 2; ++ks) {
      bf16x8 af[4], bfr[4];
      #pragma unroll
      for (int i = 0; i < 4; ++i) {
        int rowA = wm * 64 + i * 16 + cl;
        int c = ks * 4 + rg;
        af[i] = *(const bf16x8*)(ldsA + rowA * 128 + ((c ^ (rowA & 7)) * 16));
        int rowB = wn * 64 + i * 16 + cl;
        bfr[i] = *(const bf16x8*)(ldsB + rowB * 128 + ((c ^ (rowB & 7)) * 16));
      }
      #pragma unroll
      for (int mf = 0; mf < 4; ++mf)
        #pragma unroll
        for (int nf = 0; nf < 4; ++nf)
          acc[mf][nf] = __builtin_amdgcn_mfma_f32_16x16x32_bf16(af[mf], bfr[nf], acc[mf][nf], 0, 0, 0);
    }
    __syncthreads();
  }

  #pragma unroll
  for (int mf = 0; mf < 4; ++mf) {
    #pragma unroll
    for (int nf = 0; nf < 4; ++nf) {
      int n = n0 + wn * 64 + nf * 16 + cl;
      float bval = bias[n];
      int mb = m0 + wm * 64 + mf * 16 + rg * 4;
      #pragma unroll
      for (int rr = 0; rr < 4; ++rr)
        outF[(long)(mb + rr) * ldF + n] = acc[mf][nf][rr] + bval;
    }
  }
}

// ---------------- KV GEMM: 256x256 tile, BK=64, 8 waves, phase-pipelined ----------------
// (round-15 form: single A/B — runtime-selected source pointers in the staging
// path cost +24us/-8pt MfmaUtil in round 16; do not re-fold.)

#define KV_PHASE(P)                                                                   \
  {                                                                                   \
    bf16x8 a00 = dsA(cur, 2 * (P), 0),     a01 = dsA(cur, 2 * (P), 1);                \
    bf16x8 a10 = dsA(cur, 2 * (P) + 1, 0), a11 = dsA(cur, 2 * (P) + 1, 1);            \
    __builtin_amdgcn_s_setprio(1);                                                    \
    _Pragma("unroll")                                                                 \
    for (int nf = 0; nf < 4; ++nf) {                                                  \
      acc[2 * (P)][nf]     = __builtin_amdgcn_mfma_f32_16x16x32_bf16(a00, bb[nf][0], acc[2 * (P)][nf], 0, 0, 0);     \
      acc[2 * (P) + 1][nf] = __builtin_amdgcn_mfma_f32_16x16x32_bf16(a10, bb[nf][0], acc[2 * (P) + 1][nf], 0, 0, 0); \
    }                                                                                 \
    _Pragma("unroll")                                                                 \
    for (int nf = 0; nf < 4; ++nf) {                                                  \
      acc[2 * (P)][nf]     = __builtin_amdgcn_mfma_f32_16x16x32_bf16(a01, bb[nf][1], acc[2 * (P)][nf], 0, 0, 0);     \
      acc[2 * (P) + 1][nf] = __builtin_amdgcn_mfma_f32_16x16x32_bf16(a11, bb[nf][1], acc[2 * (P) + 1][nf], 0, 0, 0); \
    }                                                                                 \
    __builtin_amdgcn_s_setprio(0);                                                    \
  }

__global__ __launch_bounds__(512)
void k_gemm_kv(const bf16* __restrict__ A, const bf16* __restrict__ B,
               const float* __restrict__ bias, const int* __restrict__ nkcp,
               bf16* __restrict__ outK, bf16* __restrict__ outVT) {
  constexpr int K = 1024, NTK = 16;
  __shared__ char lds[131072];
  const int tid = threadIdx.x;
  const int w = tid >> 6, lane = tid & 63;
  const int mt = blockIdx.x >> 3, nt = blockIdx.x & 7;   // nt == XCD (hw %8)
  const int m0 = mt * 256, n0 = nt * 256;
  if (m0 >= ((*nkcp + 63) & ~63)) return;
  const int wm = w >> 2, wn = w & 3;
  const int cl = lane & 15, rg = lane >> 4;
  const int srow = lane >> 3, sg = lane & 7;

  f32x4 acc[8][4] = {};

  auto stage = [&](int b, int kt, int isB, int cr) {
    const bf16* src = isB ? B : A;
    int r = cr + w * 8 + srow;
    int gs = sg ^ (r & 7);
    const char* gp = (const char*)(src + (long)((isB ? n0 : m0) + r) * K + kt * 64) + gs * 16;
    char* lp = lds + b * 65536 + isB * 32768 + (cr + w * 8) * 128;
    gl_lds16(gp, lp);
  };
  auto dsA = [&](int b, int mf, int ks) -> bf16x8 {
    int r = wm * 128 + mf * 16 + cl;
    int c = ks * 4 + rg;
    return *(const bf16x8*)(lds + b * 65536 + r * 128 + ((c ^ (r & 7)) * 16));
  };
  auto dsB = [&](int b, int nf, int ks) -> bf16x8 {
    int r = wn * 64 + nf * 16 + cl;
    int c = ks * 4 + rg;
    return *(const bf16x8*)(lds + b * 65536 + 32768 + r * 128 + ((c ^ (r & 7)) * 16));
  };

  stage(0, 0, 1, 0);   stage(0, 0, 1, 64);
  stage(0, 0, 1, 128); stage(0, 0, 1, 192);
  stage(0, 0, 0, 0);   stage(0, 0, 0, 128);
  stage(0, 0, 0, 64);  stage(0, 0, 0, 192);

  for (int t = 0; t < NTK; ++t) {
    const int cur = t & 1, nxt = cur ^ 1;
    const bool pre = (t + 1 < NTK);
    bf16x8 bb[4][2];

    if (pre) {
      stage(nxt, t + 1, 1, 0); stage(nxt, t + 1, 1, 64);
      asm volatile("s_waitcnt vmcnt(4)\ns_barrier" ::: "memory");
    } else {
      asm volatile("s_waitcnt vmcnt(2)\ns_barrier" ::: "memory");
    }
    #pragma unroll
    for (int nf = 0; nf < 4; ++nf) { bb[nf][0] = dsB(cur, nf, 0); bb[nf][1] = dsB(cur, nf, 1); }
    KV_PHASE(0)
    if (pre) {
      stage(nxt, t + 1, 1, 128); stage(nxt, t + 1, 1, 192);
      stage(nxt, t + 1, 0, 0);   stage(nxt, t + 1, 0, 128);
    }
    KV_PHASE(1)
    if (pre) {
      stage(nxt, t + 1, 0, 64); stage(nxt, t + 1, 0, 192);
      asm volatile("s_waitcnt vmcnt(8)\ns_barrier" ::: "memory");
    } else {
      asm volatile("s_waitcnt vmcnt(0)\ns_barrier" ::: "memory");
    }
    KV_PHASE(2)
    KV_PHASE(3)
    asm volatile("s_barrier" ::: "memory");   // dbuf WAR guard
  }

  if (nt < 4) {
    #pragma unroll
    for (int mf = 0; mf < 8; ++mf)
      #pragma unroll
      for (int nf = 0; nf < 4; ++nf) {
        int n = n0 + wn * 64 + nf * 16 + cl;
        float bval = bias[n];
        int mrow = m0 + wm * 128 + mf * 16 + rg * 4;
        #pragma unroll
        for (int rr = 0; rr < 4; ++rr)
          outK[(long)(mrow + rr) * 1024 + n] = (bf16)(acc[mf][nf][rr] + bval);
      }
  } else {
    #pragma unroll
    for (int mf = 0; mf < 8; ++mf)
      #pragma unroll
      for (int nf = 0; nf < 4; ++nf) {
        int n = n0 + wn * 64 + nf * 16 + cl;
        float bval = bias[n];
        int mrow = m0 + wm * 128 + mf * 16 + rg * 4;
        bf16x4 pk;
        #pragma unroll
        for (int rr = 0; rr < 4; ++rr) pk[rr] = (bf16)(acc[mf][nf][rr] + bval);
        *(bf16x4*)(outVT + (long)(n - 1024) * SKP + mrow) = pk;
      }
  }
}

// ---------------- merged rmsnorm + rope (Q rows then K rows) ----------------

__global__ __launch_bounds__(256) void k_fuse_qk(const float* __restrict__ QP,
    bf16* __restrict__ Qr, const float* __restrict__ gq,
    const float* __restrict__ cosQ, const float* __restrict__ sinQ,
    bf16* __restrict__ KP, const float* __restrict__ gk,
    const float* __restrict__ cosK, const float* __restrict__ sinK,
    const int* __restrict__ idx, const int* __restrict__ nkcp) {
  int bid = blockIdx.x, tid = threadIdx.x;
  int d0 = tid * 4;
  __shared__ float red[4];
  float v0, v1, v2, v3;
  const float *gg, *cosT, *sinT;
  long trow;
  bool isQ = bid < SQ;
  int row;
  if (isQ) {
    row = bid;
    float4 t = *(const float4*)(QP + (long)row * DIM + d0);
    v0 = t.x; v1 = t.y; v2 = t.z; v3 = t.w;
    gg = gq; cosT = cosQ; sinT = sinQ; trow = row;
  } else {
    row = bid - SQ;
    int nkc = *nkcp;
    if (row >= ((nkc + 63) & ~63)) return;
    bf16x4 t = *(const bf16x4*)(KP + (long)row * DIM + d0);
    v0 = (float)t[0]; v1 = (float)t[1]; v2 = (float)t[2]; v3 = (float)t[3];
    gg = gk; cosT = cosK; sinT = sinK;
    trow = (row < nkc) ? idx[row] : 0;
  }
  float ss = v0 * v0 + v1 * v1 + v2 * v2 + v3 * v3;
  #pragma unroll
  for (int m = 1; m < 64; m <<= 1) ss += __shfl_xor(ss, m);
  if ((tid & 63) == 0) red[tid >> 6] = ss;
  __syncthreads();
  float rn = rsqrtf((red[0] + red[1] + red[2] + red[3]) * (1.0f / DIM) + 1e-6f);
  v0 *= rn * gg[d0]; v1 *= rn * gg[d0 + 1]; v2 *= rn * gg[d0 + 2]; v3 *= rn * gg[d0 + 3];
  int i0 = (d0 & 127) >> 1;
  float c0 = cosT[trow * HALF + i0], s0 = sinT[trow * HALF + i0];
  float c1 = cosT[trow * HALF + i0 + 1], s1 = sinT[trow * HALF + i0 + 1];
  bf16x4 o = { (bf16)(v0 * c0 - v1 * s0), (bf16)(v0 * s0 + v1 * c0),
               (bf16)(v2 * c1 - v3 * s1), (bf16)(v2 * s1 + v3 * c1) };
  if (isQ) *(bf16x4*)(Qr + (long)row * DIM + d0) = o;
  else     *(bf16x4*)(KP + (long)row * DIM + d0) = o;
}

// ---------------- flash attention: swapped QK^T + split-wait staging ----------------

__global__ __launch_bounds__(256, 2)
void k_attn(const bf16* __restrict__ Kr, const bf16* __restrict__ VT,
            const bf16* __restrict__ Qr, const int* __restrict__ nkcp,
            bf16* __restrict__ Opart, float* __restrict__ ml) {
  __shared__ char lds[51200];
  char* ldsK = lds;            // [64 keys][256 B]
  char* ldsV = lds + 16384;    // [128 d][128 B]
  int tid = threadIdx.x, w = tid >> 6, lane = tid & 63;
  char* ldsP = lds + 32768 + w * 4608;  // per-wave [32 q][144 B]
  int bid = blockIdx.x;
  int swz = (bid & 7) * 96 + (bid >> 3);  // XCD-chunked
  int sp = swz >> 5, h = (swz >> 2) & 7, qb = swz & 3;
  int nkc = *nkcp;
  int NTC = (nkc + 63) >> 6;
  int t0 = (sp * NTC) / NSPLIT;
  int t1 = ((sp + 1) * NTC) / NSPLIT;
  int cl = lane & 15, rg = lane >> 4;
  int qbase = qb * 128 + w * 32;

  bf16x8 qf[2][4];
  #pragma unroll
  for (int mf = 0; mf < 2; ++mf)
    #pragma unroll
    for (int ks = 0; ks < 4; ++ks)
      qf[mf][ks] = *(const bf16x8*)(Qr + (long)(qbase + mf * 16 + cl) * DIM + h * HD + ks * 32 + rg * 8);

  f32x4 Oa[2][8] = {};
  float m_r[2] = {-1e30f, -1e30f};
  float l_r[2] = {0.f, 0.f};

  const float sc = 0.08838834764831845f;
  for (int t = t0; t < t1; ++t) {
    int k0 = t * 64;
    __syncthreads();   // WAR: all waves done reading previous tile's K/V
    {
      int rK = lane >> 4, gK = lane & 15;
      #pragma unroll
      for (int j = 0; j < 4; ++j) {
        int rb = w * 16 + j * 4;
        int row = rb + rK;
        int gs = gK ^ (row & 7);
        gl_lds16((const char*)(Kr + (long)(k0 + row) * DIM + h * HD) + gs * 16,
                 ldsK + rb * 256);
      }
      int rV = lane >> 3, gV = lane & 7;
      #pragma unroll
      for (int j = 0; j < 4; ++j) {
        int db = w * 32 + j * 8;
        int d = db + rV;
        int gs = gV ^ (d & 7);
        gl_lds16((const char*)(VT + (long)(h * HD + d) * SKP + k0) + gs * 16,
                 ldsV + db * 128);
      }
    }
    asm volatile("s_waitcnt vmcnt(4)\ns_barrier" ::: "memory");  // K ready; V in flight

    f32x4 sa[2][4] = {};
    #pragma unroll
    for (int ks = 0; ks < 4; ++ks) {
      #pragma unroll
      for (int nf = 0; nf < 4; ++nf) {
        int key = nf * 16 + cl;
        int c = ks * 4 + rg;
        bf16x8 kb = *(const bf16x8*)(ldsK + key * 256 + ((c ^ (key & 7)) * 16));
        sa[0][nf] = __builtin_amdgcn_mfma_f32_16x16x32_bf16(kb, qf[0][ks], sa[0][nf], 0, 0, 0);
        sa[1][nf] = __builtin_amdgcn_mfma_f32_16x16x32_bf16(kb, qf[1][ks], sa[1][nf], 0, 0, 0);
      }
    }

    #pragma unroll
    for (int mf = 0; mf < 2; ++mf) {
      #pragma unroll
      for (int nf = 0; nf < 4; ++nf)
        #pragma unroll
        for (int r = 0; r < 4; ++r) {
          int key = k0 + nf * 16 + rg * 4 + r;
          sa[mf][nf][r] = (key < nkc) ? sa[mf][nf][r] * sc : -1e30f;
        }
      float mx = sa[mf][0][0];
      #pragma unroll
      for (int nf = 0; nf < 4; ++nf)
        #pragma unroll
        for (int r = 0; r < 4; ++r) mx = fmaxf(mx, sa[mf][nf][r]);
      mx = fmaxf(mx, __shfl_xor(mx, 16));
      mx = fmaxf(mx, __shfl_xor(mx, 32));
      bool grew = mx > m_r[mf] + 6.0f;
      if (__any(grew)) {
        float mn = grew ? mx : m_r[mf];
        float scl = __expf(m_r[mf] - mn);
        m_r[mf] = mn;
        l_r[mf] *= scl;
        int sb = lane & 48;
        float s0 = __shfl(scl, sb | (rg * 4 + 0));
        float s1 = __shfl(scl, sb | (rg * 4 + 1));
        float s2 = __shfl(scl, sb | (rg * 4 + 2));
        float s3 = __shfl(scl, sb | (rg * 4 + 3));
        #pragma unroll
        for (int df = 0; df < 8; ++df) {
          Oa[mf][df][0] *= s0; Oa[mf][df][1] *= s1;
          Oa[mf][df][2] *= s2; Oa[mf][df][3] *= s3;
        }
      }
      float rsum = 0.f;
      #pragma unroll
      for (int nf = 0; nf < 4; ++nf)
        #pragma unroll
        for (int r = 0; r < 4; ++r) {
          float p = __expf(sa[mf][nf][r] - m_r[mf]);
          sa[mf][nf][r] = p;
          rsum += p;
        }
      rsum += __shfl_xor(rsum, 16);
      rsum += __shfl_xor(rsum, 32);
      l_r[mf] += rsum;
      char* prow = ldsP + (mf * 16 + cl) * 144;
      #pragma unroll
      for (int nf = 0; nf < 4; ++nf) {
        bf16x4 pk = { (bf16)sa[mf][nf][0], (bf16)sa[mf][nf][1],
                      (bf16)sa[mf][nf][2], (bf16)sa[mf][nf][3] };
        *(bf16x4*)(prow + nf * 32 + rg * 8) = pk;
      }
    }

    asm volatile("s_waitcnt vmcnt(0)\ns_barrier" ::: "memory");  // V ready

    #pragma unroll
    for (int ks = 0; ks < 2; ++ks) {
      bf16x8 pa0 = *(const bf16x8*)(ldsP + cl * 144 + ks * 64 + rg * 16);
      bf16x8 pa1 = *(const bf16x8*)(ldsP + (16 + cl) * 144 + ks * 64 + rg * 16);
      int c = ks * 4 + rg;
      #pragma unroll
      for (int df = 0; df < 8; ++df) {
        int d = df * 16 + cl;
        bf16x8 vb = *(const bf16x8*)(ldsV + d * 128 + ((c ^ (d & 7)) * 16));
        Oa[0][df] = __builtin_amdgcn_mfma_f32_16x16x32_bf16(pa0, vb, Oa[0][df], 0, 0, 0);
        Oa[1][df] = __builtin_amdgcn_mfma_f32_16x16x32_bf16(pa1, vb, Oa[1][df], 0, 0, 0);
      }
    }
  }

  long rowb = (long)(sp * HEADS + h) * SQ + qbase;
  #pragma unroll
  for (int mf = 0; mf < 2; ++mf) {
    #pragma unroll
    for (int df = 0; df < 8; ++df)
      #pragma unroll
      for (int r = 0; r < 4; ++r) {
        int qr = mf * 16 + rg * 4 + r;
        Opart[(rowb + qr) * HD + df * 16 + cl] = (bf16)Oa[mf][df][r];
      }
  }
  if (rg == 0) {
    #pragma unroll
    for (int mf = 0; mf < 2; ++mf) {
      ml[(rowb + mf * 16 + cl) * 2] = m_r[mf];
      ml[(rowb + mf * 16 + cl) * 2 + 1] = l_r[mf];
    }
  }
}

__global__ __launch_bounds__(128) void k_combine(const bf16* __restrict__ Opart,
    const float* __restrict__ ml, bf16* __restrict__ AO) {
  int bid = blockIdx.x;
  int h = bid >> 9, qq = bid & 511;
  int d = threadIdx.x;
  float M = -1e30f;
  #pragma unroll 4
  for (int s2 = 0; s2 < NSPLIT; ++s2) {
    long mi = (long)(s2 * HEADS + h) * SQ + qq;
    M = fmaxf(M, ml[mi * 2]);
  }
  float L = 0.f, acc = 0.f;
  #pragma unroll 4
  for (int s2 = 0; s2 < NSPLIT; ++s2) {
    long mi = (long)(s2 * HEADS + h) * SQ + qq;
    float wgt = __expf(ml[mi * 2] - M);
    L += wgt * ml[mi * 2 + 1];
    acc += wgt * (float)Opart[mi * HD + d];
  }
  AO[(long)qq * DIM + h * HD + d] = (bf16)(acc / L);
}

// ---------------- host ----------------

extern "C" void kernel_launch(void* const* d_in, const int* in_sizes, int n_in,
                              void* d_out, int out_size, void* d_ws, size_t ws_size,
                              hipStream_t stream) {
  const float* x     = (const float*)d_in[0];
  const float* mem   = (const float*)d_in[1];
  const int*   mask  = (const int*)d_in[2];
  const float* cos_q = (const float*)d_in[3];
  const float* sin_q = (const float*)d_in[4];
  const float* cos_k = (const float*)d_in[5];
  const float* sin_k = (const float*)d_in[6];
  const float* Wq    = (const float*)d_in[7];
  const float* bq    = (const float*)d_in[8];
  const float* Wk    = (const float*)d_in[9];
  const float* bk    = (const float*)d_in[10];
  const float* Wv    = (const float*)d_in[11];
  const float* bv    = (const float*)d_in[12];
  const float* Wo    = (const float*)d_in[13];
  const float* bo    = (const float*)d_in[14];
  const float* gq    = (const float*)d_in[15];
  const float* gk    = (const float*)d_in[16];

  char* ws = (char*)d_ws;
  bf16*  memb = (bf16*)(ws + OFF_MEMB);
  bf16*  xb   = (bf16*)(ws + OFF_XB);
  bf16*  WkvB = (bf16*)(ws + OFF_WKV);
  bf16*  WqB  = (bf16*)(ws + OFF_WQ);
  bf16*  WoB  = (bf16*)(ws + OFF_WO);
  float* bKV  = (float*)(ws + OFF_BKV);
  bf16*  Kpre = (bf16*)(ws + OFF_KPRE);
  bf16*  VT   = (bf16*)(ws + OFF_VT);
  float* Qpre = (float*)(ws + OFF_QPRE);
  bf16*  Qr   = (bf16*)(ws + OFF_QR);
  bf16*  Opart= (bf16*)(ws + OFF_OP);
  float* mlb  = (float*)(ws + OFF_ML);
  bf16*  AO   = (bf16*)(ws + OFF_AO);
  int*   idx  = (int*)(ws + OFF_IDX);
  int*   nkcp = (int*)(ws + OFF_NKC);
  int*   csum = (int*)(ws + OFF_CSM);

  k_scan1<<<dim3(NCHUNK), dim3(1024), 0, stream>>>(mask, csum);
  k_scan3<<<dim3(NCHUNK), dim3(1024), 0, stream>>>(mask, csum, idx, nkcp);
  k_cvtprep<<<dim3(18048), dim3(256), 0, stream>>>(mem, idx, nkcp, memb,
      x, Wq, Wo, Wk, Wv, bk, bv, xb, WqB, WoB, WkvB, bKV);

  k_gemm<<<dim3(4 * 8), dim3(256), 0, stream>>>(xb, WqB, bq, 8, Qpre, DIM);
  k_gemm_kv<<<dim3(984), dim3(512), 0, stream>>>(memb, WkvB, bKV, nkcp, Kpre, VT);

  k_fuse_qk<<<dim3(SQ + SKP), dim3(256), 0, stream>>>(Qpre, Qr, gq, cos_q, sin_q,
      Kpre, gk, cos_k, sin_k, idx, nkcp);

  k_attn<<<dim3(NSPLIT * HEADS * 4), dim3(256), 0, stream>>>(Kpre, VT, Qr, nkcp, Opart, mlb);
  k_combine<<<dim3(HEADS * SQ), dim3(128), 0, stream>>>(Opart, mlb, AO);

  k_gemm<<<dim3(4 * 8), dim3(256), 0, stream>>>(AO, WoB, bo, 8, (float*)d_out, DIM);
  (void)in_sizes; (void)n_in; (void)out_size; (void)ws_size;
}